// Round 1
// baseline (687.268 us; speedup 1.0000x reference)
//
#include <hip/hip_runtime.h>
#include <math.h>

#define BB 2
#define NN 512
#define DH 256
#define DE 64
#define NH 8
#define EPS 1e-5f
#define NEGV (-1.0e9f)

// ---------------------------------------------------------------------------
// K1: hn = LN(h)*g+b ; qkv = hn @ Wqkv + bqkv ; scatter to q,k,vt
// 4 rows per block (amortize Wqkv L2 reads), 256 threads.
// q layout [B,H,N,32] (q pre-scaled by 1/sqrt(32)), k layout [B,H,N,32],
// vt layout [B,H,32,N] (transposed for float4 PV reads in K3b).
// ---------------------------------------------------------------------------
__global__ __launch_bounds__(256) void k1_ln_qkv(
    const float* __restrict__ h, const float* __restrict__ nh_g,
    const float* __restrict__ nh_b, const float* __restrict__ Wqkv,
    const float* __restrict__ bqkv, float* __restrict__ q,
    float* __restrict__ k, float* __restrict__ vt)
{
    __shared__ float hn[4][DH];
    const int tid = threadIdx.x;
    const int wave = tid >> 6, lane = tid & 63;
    const int row0 = blockIdx.x * 4;
    const int row = row0 + wave;

    float x[4];
    float s = 0.f, ss = 0.f;
#pragma unroll
    for (int jj = 0; jj < 4; jj++) {
        x[jj] = h[(size_t)row * DH + lane + 64 * jj];
        s += x[jj]; ss += x[jj] * x[jj];
    }
#pragma unroll
    for (int m = 32; m >= 1; m >>= 1) { s += __shfl_xor(s, m); ss += __shfl_xor(ss, m); }
    const float mean = s * (1.0f / DH);
    const float var = ss * (1.0f / DH) - mean * mean;
    const float rstd = rsqrtf(var + EPS);
#pragma unroll
    for (int jj = 0; jj < 4; jj++) {
        const int c = lane + 64 * jj;
        hn[wave][c] = (x[jj] - mean) * rstd * nh_g[c] + nh_b[c];
    }
    __syncthreads();

    float acc[4][3];
#pragma unroll
    for (int r = 0; r < 4; r++) {
        acc[r][0] = bqkv[tid];
        acc[r][1] = bqkv[tid + 256];
        acc[r][2] = bqkv[tid + 512];
    }
    for (int kk = 0; kk < DH; kk++) {
        const float w0 = Wqkv[(size_t)kk * 768 + tid];
        const float w1 = Wqkv[(size_t)kk * 768 + tid + 256];
        const float w2 = Wqkv[(size_t)kk * 768 + tid + 512];
#pragma unroll
        for (int r = 0; r < 4; r++) {
            const float hv = hn[r][kk];
            acc[r][0] += hv * w0; acc[r][1] += hv * w1; acc[r][2] += hv * w2;
        }
    }
    const float qscale = 0.17677669529663687f; // 1/sqrt(32)
    const int hh = tid >> 5, d = tid & 31;
#pragma unroll
    for (int r = 0; r < 4; r++) {
        const int rw = row0 + r;
        const int b = rw >> 9, i = rw & 511;
        q[(((size_t)(b * NH + hh) * NN) + i) * 32 + d] = acc[r][0] * qscale;
        k[(((size_t)(b * NH + hh) * NN) + i) * 32 + d] = acc[r][1];
        vt[(((size_t)(b * NH + hh) * 32) + d) * NN + i] = acc[r][2];
    }
}

// ---------------------------------------------------------------------------
// K2: en = LN(e)*g+b ; eb = LN(en @ Web + beb)*g+b -> ebias [B,H,N,N]
// 1 wave = 64 pairs (fixed b,i ; j-tile of 64). e tile staged in LDS pad-65.
// ---------------------------------------------------------------------------
__global__ __launch_bounds__(256) void k2_edge_bias(
    const float* __restrict__ e, const float* __restrict__ Web,
    const float* __restrict__ beb, const float* __restrict__ eb_g,
    const float* __restrict__ eb_b, const float* __restrict__ ne_g,
    const float* __restrict__ ne_b, float* __restrict__ ebias)
{
    __shared__ float tile[4][64][65];
    const int wave = threadIdx.x >> 6, lane = threadIdx.x & 63;
    const int t = blockIdx.x * 4 + wave;       // 8192 tiles
    const int j0 = (t & 7) * 64;
    const int bi = t >> 3;                     // b*512 + i
    const int b = bi >> 9, i = bi & 511;

    const float* src = e + ((size_t)bi * NN + j0) * DE;
#pragma unroll
    for (int it = 0; it < 16; it++) {
        const int f = it * 256 + lane * 4;
        const float4 v = *(const float4*)(src + f);
        const int r = f >> 6, c = f & 63;
        tile[wave][r][c] = v.x; tile[wave][r][c + 1] = v.y;
        tile[wave][r][c + 2] = v.z; tile[wave][r][c + 3] = v.w;
    }
    __syncthreads();

    float s = 0.f, ss = 0.f;
    for (int d = 0; d < 64; d++) {
        const float x = tile[wave][lane][d];
        s += x; ss += x * x;
    }
    const float mean = s * (1.0f / 64), var = ss * (1.0f / 64) - mean * mean;
    const float rstd = rsqrtf(var + EPS);

    float acc[8];
#pragma unroll
    for (int hh = 0; hh < 8; hh++) acc[hh] = beb[hh];
    for (int d = 0; d < 64; d++) {
        const float x = tile[wave][lane][d];
        const float en = (x - mean) * rstd * ne_g[d] + ne_b[d];
#pragma unroll
        for (int hh = 0; hh < 8; hh++) acc[hh] += en * Web[d * 8 + hh];
    }
    float s2 = 0.f, ss2 = 0.f;
#pragma unroll
    for (int hh = 0; hh < 8; hh++) { s2 += acc[hh]; ss2 += acc[hh] * acc[hh]; }
    const float m2 = s2 * 0.125f, v2 = ss2 * 0.125f - m2 * m2;
    const float r2 = rsqrtf(v2 + EPS);
#pragma unroll
    for (int hh = 0; hh < 8; hh++) {
        const float v = (acc[hh] - m2) * r2 * eb_g[hh] + eb_b[hh];
        ebias[(((size_t)(b * NH + hh) * NN) + i) * NN + j0 + lane] = v;
    }
}

// ---------------------------------------------------------------------------
// K3a: scores = q.k + ebias + pad_i + pad_j ; softmax over j ; probs in-place
// block = one (b,h,i) row; 256 threads, 2 j's each.
// ---------------------------------------------------------------------------
__global__ __launch_bounds__(256) void k3a_softmax(
    const float* __restrict__ q, const float* __restrict__ k,
    const float* __restrict__ mask, float* __restrict__ ebias)
{
    const int bh = blockIdx.x >> 9;            // b*8+h
    const int i = blockIdx.x & 511;
    const int b = bh >> 3;
    const int tid = threadIdx.x;
    const int wave = tid >> 6, lane = tid & 63;

    __shared__ __align__(16) float qrow[32];
    __shared__ float red[4];
    if (tid < 32) qrow[tid] = q[((size_t)bh * NN + i) * 32 + tid];
    __syncthreads();

    const float pad_i = (1.0f - mask[b * NN + i]) * NEGV;
    float sv[2];
#pragma unroll
    for (int u = 0; u < 2; u++) {
        const int j = tid + u * 256;
        const float4* kr = (const float4*)(k + ((size_t)bh * NN + j) * 32);
        float a = 0.f;
#pragma unroll
        for (int d4 = 0; d4 < 8; d4++) {
            const float4 kv = kr[d4];
            const float4 qv = *(const float4*)(qrow + d4 * 4);
            a += kv.x * qv.x + kv.y * qv.y + kv.z * qv.z + kv.w * qv.w;
        }
        const float pad_j = (1.0f - mask[b * NN + j]) * NEGV;
        sv[u] = a + ebias[(((size_t)bh * NN) + i) * NN + j] + pad_i + pad_j;
    }
    float mx = fmaxf(sv[0], sv[1]);
#pragma unroll
    for (int m = 32; m >= 1; m >>= 1) mx = fmaxf(mx, __shfl_xor(mx, m));
    if (lane == 0) red[wave] = mx;
    __syncthreads();
    mx = fmaxf(fmaxf(red[0], red[1]), fmaxf(red[2], red[3]));
    __syncthreads();
    const float p0 = __expf(sv[0] - mx), p1 = __expf(sv[1] - mx);
    float sm = p0 + p1;
#pragma unroll
    for (int m = 32; m >= 1; m >>= 1) sm += __shfl_xor(sm, m);
    if (lane == 0) red[wave] = sm;
    __syncthreads();
    const float inv = 1.0f / (red[0] + red[1] + red[2] + red[3]);
    ebias[(((size_t)bh * NN) + i) * NN + tid] = p0 * inv;
    ebias[(((size_t)bh * NN) + i) * NN + tid + 256] = p1 * inv;
}

// ---------------------------------------------------------------------------
// K3b: ao = probs @ v ; h_new = h + ao @ Wout + bout  -> d_out[0:262144]
// block = one (b,i); thread c = (h=c/32, d=c%32).
// ---------------------------------------------------------------------------
__global__ __launch_bounds__(256) void k3b_av_out(
    const float* __restrict__ probs, const float* __restrict__ vt,
    const float* __restrict__ h, const float* __restrict__ Wout,
    const float* __restrict__ bout, float* __restrict__ hnew)
{
    const int bi = blockIdx.x;
    const int b = bi >> 9, i = bi & 511;
    const int tid = threadIdx.x;
    __shared__ __align__(16) float p[NH * NN];
    __shared__ float ao[DH];
#pragma unroll
    for (int it = 0; it < 16; it++) {
        const int f = it * 256 + tid;
        const int hh = f >> 9, j = f & 511;
        p[f] = probs[(((size_t)(b * NH + hh) * NN) + i) * NN + j];
    }
    __syncthreads();
    const int hh = tid >> 5, d = tid & 31;
    const float* vrow = vt + (((size_t)(b * NH + hh) * 32) + d) * NN;
    float a = 0.f;
    for (int j4 = 0; j4 < 128; j4++) {
        const float4 vv = *(const float4*)(vrow + j4 * 4);
        const float4 pv = *(const float4*)(&p[hh * NN + j4 * 4]);
        a += vv.x * pv.x + vv.y * pv.y + vv.z * pv.z + vv.w * pv.w;
    }
    ao[tid] = a;
    __syncthreads();
    float out = bout[tid];
    for (int kk = 0; kk < DH; kk++) out += ao[kk] * Wout[(size_t)kk * DH + tid];
    hnew[(size_t)bi * DH + tid] = h[(size_t)bi * DH + tid] + out;
}

// ---------------------------------------------------------------------------
// K4: hW1a = h_new @ W1[0:256] + b1 ; hW1b = h_new @ W1[256:512]
// block = one (b,i) row, 64 threads (thread = out feature c).
// ---------------------------------------------------------------------------
__global__ __launch_bounds__(64) void k4_hw1(
    const float* __restrict__ hnew, const float* __restrict__ W1,
    const float* __restrict__ b1, float* __restrict__ hW1a,
    float* __restrict__ hW1b)
{
    const int row = blockIdx.x;
    const int c = threadIdx.x;
    __shared__ float hr[DH];
#pragma unroll
    for (int t = 0; t < 4; t++) hr[c + 64 * t] = hnew[(size_t)row * DH + c + 64 * t];
    __syncthreads();
    float a = b1[c], bb = 0.f;
    for (int kk = 0; kk < DH; kk++) {
        const float hv = hr[kk];
        a += hv * W1[(size_t)kk * 64 + c];
        bb += hv * W1[(size_t)(256 + kk) * 64 + c];
    }
    hW1a[(size_t)row * 64 + c] = a;
    hW1b[(size_t)row * 64 + c] = bb;
}

// ---------------------------------------------------------------------------
// K5: per pair (b,i,j): en=LN(e); t=relu(hW1a[i]+hW1b[j]+en@W1c); u=LN(t);
//     e_new = e + u@W2 + b2.   1 wave = 64 pairs, lane=pair, acc[64] static.
// Weight rows W1c[d*64+c], W2[d*64+c] are wave-uniform -> expect s_load.
// ---------------------------------------------------------------------------
__global__ __launch_bounds__(256) void k5_edge_mlp(
    const float* __restrict__ e, const float* __restrict__ ne_g,
    const float* __restrict__ ne_b, const float* __restrict__ W1c,
    const float* __restrict__ hW1a, const float* __restrict__ hW1b,
    const float* __restrict__ mlp_g, const float* __restrict__ mlp_b,
    const float* __restrict__ W2, const float* __restrict__ b2,
    float* __restrict__ enew)
{
    __shared__ float tile[4][64][65];
    const int wave = threadIdx.x >> 6, lane = threadIdx.x & 63;
    const int t = blockIdx.x * 4 + wave;
    const int j0 = (t & 7) * 64;
    const int bi = t >> 3;
    const int b = bi >> 9;

    const float* src = e + ((size_t)bi * NN + j0) * DE;
#pragma unroll
    for (int it = 0; it < 16; it++) {
        const int f = it * 256 + lane * 4;
        const float4 v = *(const float4*)(src + f);
        const int r = f >> 6, c = f & 63;
        tile[wave][r][c] = v.x; tile[wave][r][c + 1] = v.y;
        tile[wave][r][c + 2] = v.z; tile[wave][r][c + 3] = v.w;
    }
    __syncthreads();

    // LN stats over own row (pair = lane)
    float s = 0.f, ss = 0.f;
    for (int d = 0; d < 64; d++) {
        const float x = tile[wave][lane][d];
        s += x; ss += x * x;
    }
    const float mean = s * (1.0f / 64), var = ss * (1.0f / 64) - mean * mean;
    const float rstd = rsqrtf(var + EPS);
    // write en back into own row
    for (int d = 0; d < 64; d++) {
        const float x = tile[wave][lane][d];
        tile[wave][lane][d] = (x - mean) * rstd * ne_g[d] + ne_b[d];
    }

    // t init: hW1a (uniform per tile) + hW1b (per-lane row, b1 folded in hW1a)
    const float* hA = hW1a + (size_t)bi * 64;
    const float* hB = hW1b + ((size_t)(b * NN + j0 + lane)) * 64;
    float acc[64];
#pragma unroll
    for (int c4 = 0; c4 < 16; c4++) {
        const float4 ha = *(const float4*)(hA + c4 * 4);
        const float4 hb = *(const float4*)(hB + c4 * 4);
        acc[c4 * 4 + 0] = ha.x + hb.x; acc[c4 * 4 + 1] = ha.y + hb.y;
        acc[c4 * 4 + 2] = ha.z + hb.z; acc[c4 * 4 + 3] = ha.w + hb.w;
    }
    // matvec1: t += en @ W1c
    for (int d = 0; d < 64; d++) {
        const float en = tile[wave][lane][d];
        const float* w = W1c + (size_t)d * 64;
#pragma unroll
        for (int c = 0; c < 64; c++) acc[c] += en * w[c];
    }
    // relu + LN
    float s2 = 0.f, ss2 = 0.f;
#pragma unroll
    for (int c = 0; c < 64; c++) {
        acc[c] = fmaxf(acc[c], 0.f);
        s2 += acc[c]; ss2 += acc[c] * acc[c];
    }
    const float m2 = s2 * (1.0f / 64), v2 = ss2 * (1.0f / 64) - m2 * m2;
    const float r2 = rsqrtf(v2 + EPS);
    // u -> own LDS row (en dead), then acc becomes out accumulator
#pragma unroll
    for (int c = 0; c < 64; c++)
        tile[wave][lane][c] = (acc[c] - m2) * r2 * mlp_g[c] + mlp_b[c];
#pragma unroll
    for (int c = 0; c < 64; c++) acc[c] = b2[c];
    // matvec2: out += u @ W2
    for (int d = 0; d < 64; d++) {
        const float u = tile[wave][lane][d];
        const float* w = W2 + (size_t)d * 64;
#pragma unroll
        for (int c = 0; c < 64; c++) acc[c] += u * w[c];
    }
    // residual (re-read e, L2-hot) + store
    const float* erow = e + (((size_t)bi * NN) + j0 + lane) * DE;
    float* drow = enew + (((size_t)bi * NN) + j0 + lane) * DE;
#pragma unroll
    for (int c4 = 0; c4 < 16; c4++) {
        const float4 ev = *(const float4*)(erow + c4 * 4);
        float4 o;
        o.x = acc[c4 * 4 + 0] + ev.x; o.y = acc[c4 * 4 + 1] + ev.y;
        o.z = acc[c4 * 4 + 2] + ev.z; o.w = acc[c4 * 4 + 3] + ev.w;
        *(float4*)(drow + c4 * 4) = o;
    }
}

// ---------------------------------------------------------------------------
extern "C" void kernel_launch(void* const* d_in, const int* in_sizes, int n_in,
                              void* d_out, int out_size, void* d_ws, size_t ws_size,
                              hipStream_t stream)
{
    const float* h    = (const float*)d_in[0];
    const float* e    = (const float*)d_in[1];
    const float* mask = (const float*)d_in[2];
    const float* Wqkv = (const float*)d_in[3];
    const float* bqkv = (const float*)d_in[4];
    const float* Wout = (const float*)d_in[5];
    const float* bout = (const float*)d_in[6];
    const float* Web  = (const float*)d_in[7];
    const float* beb  = (const float*)d_in[8];
    const float* eb_g = (const float*)d_in[9];
    const float* eb_b = (const float*)d_in[10];
    const float* W1   = (const float*)d_in[11];
    const float* b1   = (const float*)d_in[12];
    const float* mlp_g= (const float*)d_in[13];
    const float* mlp_b= (const float*)d_in[14];
    const float* W2   = (const float*)d_in[15];
    const float* b2   = (const float*)d_in[16];
    const float* nh_g = (const float*)d_in[17];
    const float* nh_b = (const float*)d_in[18];
    const float* ne_g = (const float*)d_in[19];
    const float* ne_b = (const float*)d_in[20];

    float* ws   = (float*)d_ws;
    float* q    = ws;                      // 262144
    float* kbuf = ws + 262144;             // 262144
    float* vt   = ws + 524288;             // 262144
    float* eb   = ws + 786432;             // 4194304 (bias -> probs in place)
    float* hW1a = ws + 786432 + 4194304;   // 65536
    float* hW1b = hW1a + 65536;            // 65536

    float* hnew = (float*)d_out;           // 262144
    float* enew = hnew + 262144;           // 33554432

    hipLaunchKernelGGL(k1_ln_qkv, dim3(256), dim3(256), 0, stream,
                       h, nh_g, nh_b, Wqkv, bqkv, q, kbuf, vt);
    hipLaunchKernelGGL(k2_edge_bias, dim3(2048), dim3(256), 0, stream,
                       e, Web, beb, eb_g, eb_b, ne_g, ne_b, eb);
    hipLaunchKernelGGL(k3a_softmax, dim3(8192), dim3(256), 0, stream,
                       q, kbuf, mask, eb);
    hipLaunchKernelGGL(k3b_av_out, dim3(1024), dim3(256), 0, stream,
                       eb, vt, h, Wout, bout, hnew);
    hipLaunchKernelGGL(k4_hw1, dim3(1024), dim3(64), 0, stream,
                       hnew, W1, b1, hW1a, hW1b);
    hipLaunchKernelGGL(k5_edge_mlp, dim3(2048), dim3(256), 0, stream,
                       e, ne_g, ne_b, W1 + 512 * 64, hW1a, hW1b,
                       mlp_g, mlp_b, W2, b2, enew);
}